// Round 1
// baseline (437.508 us; speedup 1.0000x reference)
//
#include <hip/hip_runtime.h>
#include <stdint.h>

// ---------------------------------------------------------------------------
// SelfAttention (B=4, C=512, N=4096, A=512), softmax over QUERY axis (n).
// All-fp16 MFMA pipeline, z-batched, register-staged LDS, NSUB 32-k subtiles
// per barrier pair (NSUB=2 for most GEMMs; NSUB=4 for gemm3, which is
// grid-capped at 2 blocks/CU so 80 KB LDS costs no occupancy).
//   prep:   weights -> fp16; x[b][c][n] -> xT[b][n][c] fp16
//   projQK: QK[z][n][0:512]=Q+bq, [512:1024]=K+bk          (fp16)
//   projV:  Vt[z][c][m] = Wv·x + bv                         (fp16)
//   scores: S~[z][n][m] = fp16 exp(s - tile_col_max), tile col max/sum stats
//   stats_scale: lse + fs16[z][tile][m] = fp16 exp(pmax - lse)  (fused)
//   gemm3:  out[z][n][c] = x.flat + 0.1 * sum_m (S~*fs16)[n][m] Vt[c][m]
//           NSUB=4 path uses in-wave register prefetch: loads for chunk k+1
//           are issued before the MFMA phase of chunk k (latency-bound at
//           2 blocks/CU otherwise: MfmaUtil was 26.6% with HBM at 22.6%).
// Staging lane map: row = (wave<<4)|(lane&15), slot = lane>>4 so each
// 16-lane LDS write phase spans 16 distinct rows (balanced bank groups).
// ---------------------------------------------------------------------------

#define LDT 40    // padded LDS row (f16 elems) per 32-k subtile
#define SUB 5120  // 128*LDT elems per subtile

typedef _Float16 f16x8 __attribute__((ext_vector_type(8)));
typedef float f32x4 __attribute__((ext_vector_type(4)));

// ASRC: 0 = plain A; 1 = A scaled during staging by fs16[z][i0>>7][k] (gemm3)
// EPI:  1 = fp16 out + bias by col (bias0 j<512, bias1 else)  [projQK]
//       2 = fp16 out + bias by row (bias0)                     [projV]
//       3 = fp32 out = xadd[o] + alpha*acc                     [gemm3]
//       4 = fused scores: tile col stats -> pmax/psum, S~ fp16  [scores]
template <int ASRC, int EPI, int NSUB>
__global__ void __launch_bounds__(256, 2) gemm_f16(
    const _Float16* __restrict__ Ap, long lda, long zsa,
    const _Float16* __restrict__ Bp, long ldb, long zsb,
    int kslice,
    const _Float16* __restrict__ fs16, long zsl,
    float* __restrict__ outF, _Float16* __restrict__ outH, long ldc, long zso,
    const float* __restrict__ bias0, const float* __restrict__ bias1,
    const float* __restrict__ xadd,
    float* __restrict__ pmax, float* __restrict__ psum, long zsp,
    float alpha)
{
  __shared__ _Float16 smem[2 * NSUB * SUB];  // A subtiles then B subtiles

  const int z = blockIdx.z;
  const long i0 = (long)blockIdx.x * 128;
  const long j0 = (long)blockIdx.y * 128;
  const int t = (int)threadIdx.x;
  const int lane = t & 63;
  const int wv = t >> 6;
  const int quad = lane >> 4;
  const int lrow = lane & 15;
  const int wm = (wv & 1) << 6;
  const int wn = (wv >> 1) << 6;

  // staging (per 32-k subtile): wave-contiguous rows, 16B slot = lane>>4.
  // thread t covers rows r0 and r0+64, k-seg s0
  const int r0 = ((t >> 6) << 4) | (t & 15);
  const int s0 = ((t >> 4) & 3) << 3;

  const _Float16* gA0 = Ap + z * zsa + (i0 + r0) * lda + s0;
  const _Float16* gA1 = gA0 + 64 * lda;
  const _Float16* gB0 = Bp + z * zsb + (j0 + r0) * ldb + s0;
  const _Float16* gB1 = gB0 + 64 * ldb;
  const int la0 = r0 * LDT + s0;
  const int la1 = (r0 + 64) * LDT + s0;

  const _Float16* fsZ = nullptr;
  if constexpr (ASRC == 1)
    fsZ = fs16 + z * zsl + (long)blockIdx.x * 4096 + s0;

  f32x4 acc[4][4];
  const f32x4 fz = {0.f, 0.f, 0.f, 0.f};
#pragma unroll
  for (int a = 0; a < 4; a++)
#pragma unroll
    for (int b = 0; b < 4; b++) acc[a][b] = fz;

  f16x8 va[NSUB][2], vb[NSUB][2], vf[NSUB];

  auto loadChunk = [&](int kk) {
#pragma unroll
    for (int s = 0; s < NSUB; s++) {
      va[s][0] = *(const f16x8*)(gA0 + kk + 32 * s);
      va[s][1] = *(const f16x8*)(gA1 + kk + 32 * s);
      vb[s][0] = *(const f16x8*)(gB0 + kk + 32 * s);
      vb[s][1] = *(const f16x8*)(gB1 + kk + 32 * s);
      if constexpr (ASRC == 1) vf[s] = *(const f16x8*)(fsZ + kk + 32 * s);
    }
  };
  auto storeChunk = [&]() {
#pragma unroll
    for (int s = 0; s < NSUB; s++) {
      f16x8 a0 = va[s][0], a1 = va[s][1];
      if constexpr (ASRC == 1) {
        a0 = a0 * vf[s];
        a1 = a1 * vf[s];
      }
      *(f16x8*)&smem[s * SUB + la0] = a0;
      *(f16x8*)&smem[s * SUB + la1] = a1;
      *(f16x8*)&smem[(NSUB + s) * SUB + la0] = vb[s][0];
      *(f16x8*)&smem[(NSUB + s) * SUB + la1] = vb[s][1];
    }
  };
  auto mfmaChunk = [&]() {
#pragma unroll
    for (int h = 0; h < NSUB; h++) {
      const _Float16* pA = smem + h * SUB;
      const _Float16* pB = smem + (NSUB + h) * SUB;
      f16x8 fa[4], fb[4];
#pragma unroll
      for (int f = 0; f < 4; f++) {
        fa[f] = *(const f16x8*)&pA[(wm + f * 16 + lrow) * LDT + quad * 8];
        fb[f] = *(const f16x8*)&pB[(wn + f * 16 + lrow) * LDT + quad * 8];
      }
#pragma unroll
      for (int fm = 0; fm < 4; fm++)
#pragma unroll
        for (int fn = 0; fn < 4; fn++)
          acc[fm][fn] = __builtin_amdgcn_mfma_f32_16x16x32_f16(fa[fm], fb[fn], acc[fm][fn], 0, 0, 0);
    }
  };

  constexpr int KSTEP = 32 * NSUB;
  if constexpr (NSUB >= 4) {
    // register-prefetch pipeline: global loads for chunk k+1 in flight
    // during chunk k's MFMA phase (in-wave latency hiding; grid-capped
    // at 2 blocks/CU so cross-block TLP is insufficient).
    loadChunk(0);
    for (int kk = 0; kk < kslice; kk += KSTEP) {
      __syncthreads();  // all waves done reading previous tiles
      storeChunk();
      __syncthreads();
      if (kk + KSTEP < kslice) loadChunk(kk + KSTEP);
      mfmaChunk();
    }
  } else {
    for (int kk = 0; kk < kslice; kk += KSTEP) {
      loadChunk(kk);
      __syncthreads();  // all waves done reading previous tiles
      storeChunk();
      __syncthreads();
      mfmaChunk();
    }
  }

  // D frag: col(j) = lane&15 (+wn+fn*16), row(i) = quad*4 + reg (+wm+fm*16)
  const long obase = (long)z * zso;

  if constexpr (EPI == 1 || EPI == 2) {
#pragma unroll
    for (int fm = 0; fm < 4; fm++) {
      const long gi0 = i0 + wm + fm * 16 + quad * 4;
#pragma unroll
      for (int fn = 0; fn < 4; fn++) {
        const long gj = j0 + wn + fn * 16 + lrow;
        float badd = 0.f;
        if constexpr (EPI == 1) badd = (gj < 512) ? bias0[gj] : bias1[gj - 512];
#pragma unroll
        for (int r = 0; r < 4; r++) {
          float v = acc[fm][fn][r];
          if constexpr (EPI == 1) v += badd;
          else v += bias0[gi0 + r];
          outH[obase + (gi0 + r) * ldc + gj] = (_Float16)v;
        }
      }
    }
  } else if constexpr (EPI == 3) {
#pragma unroll
    for (int fm = 0; fm < 4; fm++) {
      const long gi0 = i0 + wm + fm * 16 + quad * 4;
#pragma unroll
      for (int fn = 0; fn < 4; fn++) {
        const long gj = j0 + wn + fn * 16 + lrow;
#pragma unroll
        for (int r = 0; r < 4; r++) {
          const long o = obase + (gi0 + r) * ldc + gj;
          outF[o] = fmaf(alpha, acc[fm][fn][r], xadd[o]);
        }
      }
    }
  } else {  // EPI == 4: single-exp fused scores epilogue
    __syncthreads();  // done with K-loop LDS
    float* Ls = (float*)smem;
    // LDS float layout: [0,1024) partials (max, then reused for sums)
    //                   [1024,1280) half-maxes, [1280,1408) Mcol
    // stage 1: per-lane per-column-group MAX only (no exp)
#pragma unroll
    for (int fn = 0; fn < 4; fn++) {
      float mx = -3.4e38f;
#pragma unroll
      for (int fm = 0; fm < 4; fm++)
#pragma unroll
        for (int r = 0; r < 4; r++) mx = fmaxf(mx, acc[fm][fn][r]);
      Ls[(wv * 4 + quad) * 64 + fn * 16 + lrow] = mx;
    }
    __syncthreads();
    // stage 2: combine 4 quads -> per (row-half h, col c) max
    {
      const int c = t & 127;
      const int h = t >> 7;
      const int wvv = ((c >> 6) << 1) + h;
      const int wc = c & 63;
      float M = -3.4e38f;
#pragma unroll
      for (int q = 0; q < 4; q++) M = fmaxf(M, Ls[(wvv * 4 + q) * 64 + wc]);
      Ls[1024 + h * 128 + c] = M;
    }
    __syncthreads();
    // stage 3: column max; store pmax; park Mcol in LDS
    if (t < 128) {
      float Mcol = fmaxf(Ls[1024 + t], Ls[1152 + t]);
      pmax[z * zsp + (long)blockIdx.x * 4096 + j0 + t] = Mcol;
      Ls[1280 + t] = Mcol;
    }
    __syncthreads();
    // stage 4: single exp pass — store S~ AND accumulate column partial sums
#pragma unroll
    for (int fn = 0; fn < 4; fn++) {
      const int colc = wn + fn * 16 + lrow;
      const float Mcol = Ls[1280 + colc];
      const long gj = j0 + colc;
      float sm = 0.f;
#pragma unroll
      for (int fm = 0; fm < 4; fm++) {
        const long gi0 = i0 + wm + fm * 16 + quad * 4;
#pragma unroll
        for (int r = 0; r < 4; r++) {
          float e = __expf(acc[fm][fn][r] - Mcol);
          sm += e;
          outH[obase + (gi0 + r) * ldc + gj] = (_Float16)e;
        }
      }
      Ls[(wv * 4 + quad) * 64 + fn * 16 + lrow] = sm;  // reuse partial region
    }
    __syncthreads();
    // stage 5: pure-add reduce of 8 partials per column -> psum
    if (t < 128) {
      const int wc = t & 63;
      const int ch = t >> 6;
      float s = 0.f;
#pragma unroll
      for (int h = 0; h < 2; h++) {
        const int wvv = (ch << 1) + h;
#pragma unroll
        for (int q = 0; q < 4; q++) s += Ls[(wvv * 4 + q) * 64 + wc];
      }
      psum[z * zsp + (long)blockIdx.x * 4096 + j0 + t] = s;
    }
  }
}

__global__ void convert_weights(const float* __restrict__ Wq, const float* __restrict__ Wk,
                                const float* __restrict__ Wv,
                                _Float16* __restrict__ WQK, _Float16* __restrict__ Wv16)
{
  int idx = blockIdx.x * 256 + threadIdx.x;  // 0..786431
  if (idx < 524288)
    WQK[idx] = (_Float16)((idx < 262144) ? Wq[idx] : Wk[idx - 262144]);
  else
    Wv16[idx - 524288] = (_Float16)Wv[idx - 524288];
}

// x [b][c][n] fp32 -> xT [b][n][c] fp16
__global__ void transpose_x(const float* __restrict__ x, _Float16* __restrict__ xT)
{
  __shared__ float tile[32][33];
  const int b = blockIdx.z;
  const int n0 = blockIdx.x * 32;
  const int c0 = blockIdx.y * 32;
  const int tx = threadIdx.x;
  const int ty = threadIdx.y;
  const float* xb = x + (long)b * 2097152;
#pragma unroll
  for (int k = 0; k < 4; k++)
    tile[ty + k * 8][tx] = xb[(long)(c0 + ty + k * 8) * 4096 + n0 + tx];
  __syncthreads();
  _Float16* xTb = xT + (long)b * 2097152;
#pragma unroll
  for (int k = 0; k < 4; k++)
    xTb[(long)(n0 + ty + k * 8) * 512 + c0 + tx] = (_Float16)tile[tx][ty + k * 8];
}

// fused: lse[z][m] from 32 tile partials, then fs16[z][tile][m] = exp(pmax-lse)
__global__ void stats_scale(const float* __restrict__ pmax, const float* __restrict__ psum,
                            _Float16* __restrict__ fs16)
{
  const int idx = blockIdx.x * 256 + threadIdx.x;  // grid 64: z*4096+m
  const int z = idx >> 12;
  const int m = idx & 4095;
  const float* pm = pmax + (long)z * 131072 + m;
  const float* ps = psum + (long)z * 131072 + m;
  float M = -3.4e38f, S = 0.f;
  for (int i = 0; i < 32; i++) {
    float m2 = pm[(long)i * 4096], s2 = ps[(long)i * 4096];
    float nm = fmaxf(M, m2);
    S = S * __expf(M - nm) + s2 * __expf(m2 - nm);
    M = nm;
  }
  const float lse = M + __logf(S);
  _Float16* fo = fs16 + (long)z * 131072 + m;
  for (int i = 0; i < 32; i++)
    fo[(long)i * 4096] = (_Float16)__expf(pm[(long)i * 4096] - lse);
}

extern "C" void kernel_launch(void* const* d_in, const int* in_sizes, int n_in,
                              void* d_out, int out_size, void* d_ws, size_t ws_size,
                              hipStream_t stream)
{
  const float* x  = (const float*)d_in[0];
  const float* Wq = (const float*)d_in[1];
  const float* bq = (const float*)d_in[2];
  const float* Wk = (const float*)d_in[3];
  const float* bk = (const float*)d_in[4];
  const float* Wv = (const float*)d_in[5];
  const float* bv = (const float*)d_in[6];
  float* out = (float*)d_out;

  char* w = (char*)d_ws;
  _Float16* WQK   = (_Float16*)(w + 0);          //  1,048,576
  _Float16* Wv16  = (_Float16*)(w + 1048576);    //    524,288
  _Float16* xT    = (_Float16*)(w + 1572864);    // 16,777,216
  _Float16* QK    = (_Float16*)(w + 18350080);   // 33,554,432
  _Float16* Vt    = (_Float16*)(w + 51904512);   // 16,777,216
  float*    pmaxB = (float*)   (w + 68747264);   //  2,097,152
  float*    psumB = (float*)   (w + 70844416);   //  2,097,152
  _Float16* fs16  = (_Float16*)(w + 72941568);   //  1,048,576 = [z][32][4096] fp16
  _Float16* S16   = (_Float16*)(w + 75038720);   // 134,217,728
  // total 209,256,448 B

  convert_weights<<<3072, 256, 0, stream>>>(Wq, Wk, Wv, WQK, Wv16);
  transpose_x<<<dim3(128, 16, 4), dim3(32, 8), 0, stream>>>(x, xT);

  // projQK: QK[z][n][j] fp16, j<512 Q(+bq), j>=512 K(+bk)
  gemm_f16<0, 1, 2><<<dim3(32, 8, 4), 256, 0, stream>>>(
      xT, 512, 2097152L, WQK, 512, 0L, 512, nullptr, 0L,
      nullptr, QK, 1024, 4194304L, bq, bk, nullptr, nullptr, nullptr, 0L, 0.f);
  // projV: Vt[z][c][m] fp16 (+bv by row)
  gemm_f16<0, 2, 2><<<dim3(4, 32, 4), 256, 0, stream>>>(
      Wv16, 512, 0L, xT, 512, 2097152L, 512, nullptr, 0L,
      nullptr, Vt, 4096, 2097152L, bv, nullptr, nullptr, nullptr, nullptr, 0L, 0.f);
  // scores: S~[z][n][m] fp16 + tile col stats (single-exp epilogue)
  gemm_f16<0, 4, 2><<<dim3(32, 32, 4), 256, 0, stream>>>(
      QK, 1024, 4194304L, QK + 512, 1024, 4194304L, 512, nullptr, 0L,
      nullptr, S16, 4096, 16777216L, nullptr, nullptr, nullptr,
      pmaxB, psumB, 131072L, 0.f);
  stats_scale<<<64, 256, 0, stream>>>(pmaxB, psumB, fs16);
  // gemm3 (NSUB=4: 80 KB LDS, grid-capped 2 blocks/CU anyway; register
  // prefetch pipeline): out = x.flat + 0.1 * (S~*fs16) · Vt^T
  gemm_f16<1, 3, 4><<<dim3(32, 4, 4), 256, 0, stream>>>(
      S16, 4096, 16777216L, Vt, 4096, 2097152L, 4096, fs16, 131072L,
      out, nullptr, 512, 2097152L, nullptr, nullptr, x, nullptr, nullptr, 0L, 0.1f);
}

// Round 2
// 325.414 us; speedup vs baseline: 1.3445x; 1.3445x over previous
//
#include <hip/hip_runtime.h>
#include <stdint.h>

// ---------------------------------------------------------------------------
// SelfAttention (B=4, C=512, N=4096, A=512), softmax over QUERY axis (n).
// All-fp16 MFMA pipeline, z-batched.
//   prep:   weights -> fp16; x[b][c][n] -> xT[b][n][c] fp16
//   projQK: QK[z][n][0:512]=Q+bq, [512:1024]=K+bk          (fp16)
//   projV:  Vt[z][c][m] = Wv·x + bv                         (fp16)
//   scores: S~[z][n][m] = fp16 exp(s - tile_col_max), tile col max/sum stats
//   stats_scale: lse + fs16[z][tile][m] = fp16 exp(pmax - lse)  (fused)
//   gemm3:  out[z][n][c] = x.flat + 0.1 * sum_m (S~*fs16)[n][m] Vt[c][m]
//
// Two staging modes (template STG):
//   STG=0: reg-staged LDS (round-0 coalesced lane map: 4 lanes x 64B per row;
//          LDT=40 padded rows), 2-barrier loop. Used by projQK/projV/scores.
//   STG=1: global_load_lds DMA + double-buffered LDS, single barrier+vmcnt(0)
//          per K-step; prefetch of chunk k+1 stays in flight through chunk
//          k's 32-MFMA phase (in-wave latency hiding that regalloc cannot
//          defeat — round-1's register prefetch was sunk by the scheduler,
//          VGPR stayed 96 and MfmaUtil dropped to 17%). LDS is linear
//          [128][32] per subtile (DMA writes base+lane*16); bank spread via
//          XOR slot swizzle applied on the GLOBAL source address (stage:
//          slot_data = (l&3)^((l>>3)&3)) and on the ds_read slot
//          (quad ^ ((lrow>>1)&3)) — 8 lanes per bank-quad, b128 minimum.
//          fs16 scale moves to fragment-read time; fsv loads issue BEFORE
//          the stage intrinsics (sched_barrier pin) so their wait is
//          vmcnt(8), never draining the prefetch. Used by gemm3.
// ---------------------------------------------------------------------------

#define LDT 40    // padded LDS row (f16 elems) per 32-k subtile (STG=0)
#define SUB 5120  // 128*LDT elems per subtile (STG=0)

typedef _Float16 f16x8 __attribute__((ext_vector_type(8)));
typedef float f32x4 __attribute__((ext_vector_type(4)));

__device__ __forceinline__ void async16(const _Float16* g, _Float16* l)
{
  __builtin_amdgcn_global_load_lds(
      (const __attribute__((address_space(1))) void*)g,
      (__attribute__((address_space(3))) void*)l, 16, 0, 0);
}

// ASRC: 0 = plain A; 1 = A scaled by fs16[z][i0>>7][k] (gemm3)
// EPI:  1 = fp16 out + bias by col (bias0 j<512, bias1 else)  [projQK]
//       2 = fp16 out + bias by row (bias0)                     [projV]
//       3 = fp32 out = xadd[o] + alpha*acc                     [gemm3]
//       4 = fused scores: tile col stats -> pmax/psum, S~ fp16  [scores]
template <int ASRC, int EPI, int NSUB, int STG>
__global__ void __launch_bounds__(256, 2) gemm_f16(
    const _Float16* __restrict__ Ap, long lda, long zsa,
    const _Float16* __restrict__ Bp, long ldb, long zsb,
    int kslice,
    const _Float16* __restrict__ fs16, long zsl,
    float* __restrict__ outF, _Float16* __restrict__ outH, long ldc, long zso,
    const float* __restrict__ bias0, const float* __restrict__ bias1,
    const float* __restrict__ xadd,
    float* __restrict__ pmax, float* __restrict__ psum, long zsp,
    float alpha)
{
  constexpr int SMEM_E = (STG == 1) ? (4 * NSUB * 4096) : (2 * NSUB * SUB);
  __shared__ _Float16 smem[SMEM_E];

  const int z = blockIdx.z;
  const long i0 = (long)blockIdx.x * 128;
  const long j0 = (long)blockIdx.y * 128;
  const int t = (int)threadIdx.x;
  const int lane = t & 63;
  const int wv = t >> 6;
  const int quad = lane >> 4;
  const int lrow = lane & 15;
  const int wm = (wv & 1) << 6;
  const int wn = (wv >> 1) << 6;

  f32x4 acc[4][4];
  const f32x4 fz = {0.f, 0.f, 0.f, 0.f};
#pragma unroll
  for (int a = 0; a < 4; a++)
#pragma unroll
    for (int b = 0; b < 4; b++) acc[a][b] = fz;

  if constexpr (STG == 0) {
    // ---------- round-0 reg-staged path (coalesced lane map) ----------
    const int r0 = t >> 2;
    const int s0 = (t & 3) << 3;

    const _Float16* gA0 = Ap + z * zsa + (i0 + r0) * lda + s0;
    const _Float16* gA1 = gA0 + 64 * lda;
    const _Float16* gB0 = Bp + z * zsb + (j0 + r0) * ldb + s0;
    const _Float16* gB1 = gB0 + 64 * ldb;
    const int la0 = r0 * LDT + s0;
    const int la1 = (r0 + 64) * LDT + s0;

    const _Float16* fsZ = nullptr;
    if constexpr (ASRC == 1)
      fsZ = fs16 + z * zsl + (long)blockIdx.x * 4096 + s0;

    for (int kk = 0; kk < kslice; kk += 32 * NSUB) {
      // 8*NSUB loads batched in flight; overlap previous iteration's MFMA
      f16x8 va[NSUB][2], vb[NSUB][2];
#pragma unroll
      for (int s = 0; s < NSUB; s++) {
        va[s][0] = *(const f16x8*)(gA0 + kk + 32 * s);
        va[s][1] = *(const f16x8*)(gA1 + kk + 32 * s);
        vb[s][0] = *(const f16x8*)(gB0 + kk + 32 * s);
        vb[s][1] = *(const f16x8*)(gB1 + kk + 32 * s);
      }
      if constexpr (ASRC == 1) {
#pragma unroll
        for (int s = 0; s < NSUB; s++) {
          const f16x8 fsv = *(const f16x8*)(fsZ + kk + 32 * s);
          va[s][0] = va[s][0] * fsv;
          va[s][1] = va[s][1] * fsv;
        }
      }
      __syncthreads();  // all waves done reading previous tiles
#pragma unroll
      for (int s = 0; s < NSUB; s++) {
        *(f16x8*)&smem[s * SUB + la0] = va[s][0];
        *(f16x8*)&smem[s * SUB + la1] = va[s][1];
        *(f16x8*)&smem[(NSUB + s) * SUB + la0] = vb[s][0];
        *(f16x8*)&smem[(NSUB + s) * SUB + la1] = vb[s][1];
      }
      __syncthreads();

#pragma unroll
      for (int h = 0; h < NSUB; h++) {
        const _Float16* pA = smem + h * SUB;
        const _Float16* pB = smem + (NSUB + h) * SUB;
        f16x8 fa[4], fb[4];
#pragma unroll
        for (int f = 0; f < 4; f++) {
          fa[f] = *(const f16x8*)&pA[(wm + f * 16 + lrow) * LDT + quad * 8];
          fb[f] = *(const f16x8*)&pB[(wn + f * 16 + lrow) * LDT + quad * 8];
        }
#pragma unroll
        for (int fm = 0; fm < 4; fm++)
#pragma unroll
          for (int fn = 0; fn < 4; fn++)
            acc[fm][fn] = __builtin_amdgcn_mfma_f32_16x16x32_f16(fa[fm], fb[fn], acc[fm][fn], 0, 0, 0);
      }
    }
  } else {
    // ---------- STG=1: global_load_lds DMA + dbuf 2-phase ----------
    constexpr int KSTEP = 32 * NSUB;
    constexpr int BUFE = 2 * NSUB * 4096;  // f16 elems per buffer (A+B)
    const int crow = lane >> 2;                            // row within 16-row chunk
    const int ks8 = (((lane & 3) ^ ((lane >> 3) & 3)) << 3);  // inverse-swizzled k slot

    // wave wv stages chunks wv (rows 16wv..+15) and wv+4 (rows 64+16wv..+15)
    const _Float16* gAc0 = Ap + z * zsa + (i0 + 16 * wv + crow) * lda + ks8;
    const _Float16* gAc1 = gAc0 + 64 * lda;
    const _Float16* gBc0 = Bp + z * zsb + (j0 + 16 * wv + crow) * ldb + ks8;
    const _Float16* gBc1 = gBc0 + 64 * ldb;
    _Float16* ldsC0 = smem + wv * 512;        // chunk wv dest (wave-uniform)
    _Float16* ldsC1 = smem + (wv + 4) * 512;  // chunk wv+4 dest

    const _Float16* fsZq = nullptr;
    if constexpr (ASRC == 1)
      fsZq = fs16 + z * zsl + (long)blockIdx.x * 4096 + quad * 8;

    // swizzled read slot: data for k-slice quad*8 sits at slot quad^((lrow>>1)&3)
    const int qs = ((quad ^ ((lrow >> 1) & 3)) << 3);

    auto stage = [&](int buf, int kk) {
#pragma unroll
      for (int s = 0; s < NSUB; s++) {
        const int ab = buf * BUFE + s * 4096;
        const int bb = buf * BUFE + (NSUB + s) * 4096;
        async16(gAc0 + kk + 32 * s, ldsC0 + ab);
        async16(gAc1 + kk + 32 * s, ldsC1 + ab);
        async16(gBc0 + kk + 32 * s, ldsC0 + bb);
        async16(gBc1 + kk + 32 * s, ldsC1 + bb);
      }
    };

    stage(0, 0);
    __syncthreads();  // drains vmcnt(0): buf0 ready
    int cur = 0;
    for (int kk = 0; kk < kslice; kk += KSTEP) {
      f16x8 fsv[NSUB];
      if constexpr (ASRC == 1) {
#pragma unroll
        for (int h = 0; h < NSUB; h++)
          fsv[h] = *(const f16x8*)(fsZq + kk + 32 * h);
        // pin fsv issue BEFORE the stage intrinsics: their waitcnt is then
        // vmcnt(8) and never drains the prefetch mid-compute.
        __builtin_amdgcn_sched_barrier(0);
      }
      if (kk + KSTEP < kslice) stage(cur ^ 1, kk + KSTEP);  // prefetch in flight
#pragma unroll
      for (int h = 0; h < NSUB; h++) {
        const _Float16* pA = smem + cur * BUFE + h * 4096;
        const _Float16* pB = smem + cur * BUFE + (NSUB + h) * 4096;
        f16x8 fa[4], fb[4];
#pragma unroll
        for (int f = 0; f < 4; f++) {
          fa[f] = *(const f16x8*)&pA[(wm + f * 16 + lrow) * 32 + qs];
          fb[f] = *(const f16x8*)&pB[(wn + f * 16 + lrow) * 32 + qs];
        }
        if constexpr (ASRC == 1) {
#pragma unroll
          for (int f = 0; f < 4; f++) fa[f] = fa[f] * fsv[h];
        }
#pragma unroll
        for (int fm = 0; fm < 4; fm++)
#pragma unroll
          for (int fn = 0; fn < 4; fn++)
            acc[fm][fn] = __builtin_amdgcn_mfma_f32_16x16x32_f16(fa[fm], fb[fn], acc[fm][fn], 0, 0, 0);
      }
      // one drain per K-step: prefetch had the whole MFMA phase in flight;
      // also fences buf[cur] reads before it is re-staged next iteration.
      __syncthreads();
      cur ^= 1;
    }
  }

  // D frag: col(j) = lane&15 (+wn+fn*16), row(i) = quad*4 + reg (+wm+fm*16)
  const long obase = (long)z * zso;

  if constexpr (EPI == 1 || EPI == 2) {
#pragma unroll
    for (int fm = 0; fm < 4; fm++) {
      const long gi0 = i0 + wm + fm * 16 + quad * 4;
#pragma unroll
      for (int fn = 0; fn < 4; fn++) {
        const long gj = j0 + wn + fn * 16 + lrow;
        float badd = 0.f;
        if constexpr (EPI == 1) badd = (gj < 512) ? bias0[gj] : bias1[gj - 512];
#pragma unroll
        for (int r = 0; r < 4; r++) {
          float v = acc[fm][fn][r];
          if constexpr (EPI == 1) v += badd;
          else v += bias0[gi0 + r];
          outH[obase + (gi0 + r) * ldc + gj] = (_Float16)v;
        }
      }
    }
  } else if constexpr (EPI == 3) {
#pragma unroll
    for (int fm = 0; fm < 4; fm++) {
      const long gi0 = i0 + wm + fm * 16 + quad * 4;
#pragma unroll
      for (int fn = 0; fn < 4; fn++) {
        const long gj = j0 + wn + fn * 16 + lrow;
#pragma unroll
        for (int r = 0; r < 4; r++) {
          const long o = obase + (gi0 + r) * ldc + gj;
          outF[o] = fmaf(alpha, acc[fm][fn][r], xadd[o]);
        }
      }
    }
  } else {  // EPI == 4: single-exp fused scores epilogue
    __syncthreads();  // done with K-loop LDS
    float* Ls = (float*)smem;
    // LDS float layout: [0,1024) partials (max, then reused for sums)
    //                   [1024,1280) half-maxes, [1280,1408) Mcol
    // stage 1: per-lane per-column-group MAX only (no exp)
#pragma unroll
    for (int fn = 0; fn < 4; fn++) {
      float mx = -3.4e38f;
#pragma unroll
      for (int fm = 0; fm < 4; fm++)
#pragma unroll
        for (int r = 0; r < 4; r++) mx = fmaxf(mx, acc[fm][fn][r]);
      Ls[(wv * 4 + quad) * 64 + fn * 16 + lrow] = mx;
    }
    __syncthreads();
    // stage 2: combine 4 quads -> per (row-half h, col c) max
    {
      const int c = t & 127;
      const int h = t >> 7;
      const int wvv = ((c >> 6) << 1) + h;
      const int wc = c & 63;
      float M = -3.4e38f;
#pragma unroll
      for (int q = 0; q < 4; q++) M = fmaxf(M, Ls[(wvv * 4 + q) * 64 + wc]);
      Ls[1024 + h * 128 + c] = M;
    }
    __syncthreads();
    // stage 3: column max; store pmax; park Mcol in LDS
    if (t < 128) {
      float Mcol = fmaxf(Ls[1024 + t], Ls[1152 + t]);
      pmax[z * zsp + (long)blockIdx.x * 4096 + j0 + t] = Mcol;
      Ls[1280 + t] = Mcol;
    }
    __syncthreads();
    // stage 4: single exp pass — store S~ AND accumulate column partial sums
#pragma unroll
    for (int fn = 0; fn < 4; fn++) {
      const int colc = wn + fn * 16 + lrow;
      const float Mcol = Ls[1280 + colc];
      const long gj = j0 + colc;
      float sm = 0.f;
#pragma unroll
      for (int fm = 0; fm < 4; fm++) {
        const long gi0 = i0 + wm + fm * 16 + quad * 4;
#pragma unroll
        for (int r = 0; r < 4; r++) {
          float e = __expf(acc[fm][fn][r] - Mcol);
          sm += e;
          outH[obase + (gi0 + r) * ldc + gj] = (_Float16)e;
        }
      }
      Ls[(wv * 4 + quad) * 64 + fn * 16 + lrow] = sm;  // reuse partial region
    }
    __syncthreads();
    // stage 5: pure-add reduce of 8 partials per column -> psum
    if (t < 128) {
      const int wc = t & 63;
      const int ch = t >> 6;
      float s = 0.f;
#pragma unroll
      for (int h = 0; h < 2; h++) {
        const int wvv = (ch << 1) + h;
#pragma unroll
        for (int q = 0; q < 4; q++) s += Ls[(wvv * 4 + q) * 64 + wc];
      }
      psum[z * zsp + (long)blockIdx.x * 4096 + j0 + t] = s;
    }
  }
}

__global__ void convert_weights(const float* __restrict__ Wq, const float* __restrict__ Wk,
                                const float* __restrict__ Wv,
                                _Float16* __restrict__ WQK, _Float16* __restrict__ Wv16)
{
  int idx = blockIdx.x * 256 + threadIdx.x;  // 0..786431
  if (idx < 524288)
    WQK[idx] = (_Float16)((idx < 262144) ? Wq[idx] : Wk[idx - 262144]);
  else
    Wv16[idx - 524288] = (_Float16)Wv[idx - 524288];
}

// x [b][c][n] fp32 -> xT [b][n][c] fp16
__global__ void transpose_x(const float* __restrict__ x, _Float16* __restrict__ xT)
{
  __shared__ float tile[32][33];
  const int b = blockIdx.z;
  const int n0 = blockIdx.x * 32;
  const int c0 = blockIdx.y * 32;
  const int tx = threadIdx.x;
  const int ty = threadIdx.y;
  const float* xb = x + (long)b * 2097152;
#pragma unroll
  for (int k = 0; k < 4; k++)
    tile[ty + k * 8][tx] = xb[(long)(c0 + ty + k * 8) * 4096 + n0 + tx];
  __syncthreads();
  _Float16* xTb = xT + (long)b * 2097152;
#pragma unroll
  for (int k = 0; k < 4; k++)
    xTb[(long)(n0 + ty + k * 8) * 512 + c0 + tx] = (_Float16)tile[tx][ty + k * 8];
}

// fused: lse[z][m] from 32 tile partials, then fs16[z][tile][m] = exp(pmax-lse)
__global__ void stats_scale(const float* __restrict__ pmax, const float* __restrict__ psum,
                            _Float16* __restrict__ fs16)
{
  const int idx = blockIdx.x * 256 + threadIdx.x;  // grid 64: z*4096+m
  const int z = idx >> 12;
  const int m = idx & 4095;
  const float* pm = pmax + (long)z * 131072 + m;
  const float* ps = psum + (long)z * 131072 + m;
  float M = -3.4e38f, S = 0.f;
  for (int i = 0; i < 32; i++) {
    float m2 = pm[(long)i * 4096], s2 = ps[(long)i * 4096];
    float nm = fmaxf(M, m2);
    S = S * __expf(M - nm) + s2 * __expf(m2 - nm);
    M = nm;
  }
  const float lse = M + __logf(S);
  _Float16* fo = fs16 + (long)z * 131072 + m;
  for (int i = 0; i < 32; i++)
    fo[(long)i * 4096] = (_Float16)__expf(pm[(long)i * 4096] - lse);
}

extern "C" void kernel_launch(void* const* d_in, const int* in_sizes, int n_in,
                              void* d_out, int out_size, void* d_ws, size_t ws_size,
                              hipStream_t stream)
{
  const float* x  = (const float*)d_in[0];
  const float* Wq = (const float*)d_in[1];
  const float* bq = (const float*)d_in[2];
  const float* Wk = (const float*)d_in[3];
  const float* bk = (const float*)d_in[4];
  const float* Wv = (const float*)d_in[5];
  const float* bv = (const float*)d_in[6];
  float* out = (float*)d_out;

  char* w = (char*)d_ws;
  _Float16* WQK   = (_Float16*)(w + 0);          //  1,048,576
  _Float16* Wv16  = (_Float16*)(w + 1048576);    //    524,288
  _Float16* xT    = (_Float16*)(w + 1572864);    // 16,777,216
  _Float16* QK    = (_Float16*)(w + 18350080);   // 33,554,432
  _Float16* Vt    = (_Float16*)(w + 51904512);   // 16,777,216
  float*    pmaxB = (float*)   (w + 68747264);   //  2,097,152
  float*    psumB = (float*)   (w + 70844416);   //  2,097,152
  _Float16* fs16  = (_Float16*)(w + 72941568);   //  1,048,576 = [z][32][4096] fp16
  _Float16* S16   = (_Float16*)(w + 75038720);   // 134,217,728
  // total 209,256,448 B

  convert_weights<<<3072, 256, 0, stream>>>(Wq, Wk, Wv, WQK, Wv16);
  transpose_x<<<dim3(128, 16, 4), dim3(32, 8), 0, stream>>>(x, xT);

  // projQK: QK[z][n][j] fp16, j<512 Q(+bq), j>=512 K(+bk)
  gemm_f16<0, 1, 2, 0><<<dim3(32, 8, 4), 256, 0, stream>>>(
      xT, 512, 2097152L, WQK, 512, 0L, 512, nullptr, 0L,
      nullptr, QK, 1024, 4194304L, bq, bk, nullptr, nullptr, nullptr, 0L, 0.f);
  // projV: Vt[z][c][m] fp16 (+bv by row)
  gemm_f16<0, 2, 2, 0><<<dim3(4, 32, 4), 256, 0, stream>>>(
      Wv16, 512, 0L, xT, 512, 2097152L, 512, nullptr, 0L,
      nullptr, Vt, 4096, 2097152L, bv, nullptr, nullptr, nullptr, nullptr, 0L, 0.f);
  // scores: S~[z][n][m] fp16 + tile col stats (single-exp epilogue)
  gemm_f16<0, 4, 2, 0><<<dim3(32, 32, 4), 256, 0, stream>>>(
      QK, 1024, 4194304L, QK + 512, 1024, 4194304L, 512, nullptr, 0L,
      nullptr, S16, 4096, 16777216L, nullptr, nullptr, nullptr,
      pmaxB, psumB, 131072L, 0.f);
  stats_scale<<<64, 256, 0, stream>>>(pmaxB, psumB, fs16);
  // gemm3 (STG=1: global_load_lds dbuf 2-phase, K-step 64, 64 KB LDS,
  // 2 blocks/CU — grid-capped anyway): out = x.flat + 0.1*(S~*fs16)·Vt^T
  gemm_f16<1, 3, 2, 1><<<dim3(32, 4, 4), 256, 0, stream>>>(
      S16, 4096, 16777216L, Vt, 4096, 2097152L, 4096, fs16, 131072L,
      out, nullptr, 512, 2097152L, nullptr, nullptr, x, nullptr, nullptr, 0L, 0.1f);
}

// Round 4
// 310.946 us; speedup vs baseline: 1.4070x; 1.0465x over previous
//
#include <hip/hip_runtime.h>
#include <stdint.h>

// ---------------------------------------------------------------------------
// SelfAttention (B=4, C=512, N=4096, A=512), softmax over QUERY axis (n).
// All-fp16 MFMA pipeline, z-batched.
//   prep:   weights -> fp16; x[b][c][n] -> xT[b][n][c] fp16
//   projQK: QK[z][n][0:512]=Q+bq, [512:1024]=K+bk          (fp16)
//   projV:  Vt[z][c][m] = Wv·x + bv                         (fp16)
//   scores: S~[z][n][m] = fp16 exp(s - tile_col_max), tile col max/sum stats
//   stats_scale: lse + fs16[z][tile][m] = fp16 exp(pmax - lse)  (fused)
//   gemm3:  out[z][n][c] = x.flat + 0.1 * sum_m (S~*fs16)[n][m] Vt[c][m]
//
// Two staging modes (template STG):
//   STG=0: reg-staged LDS (coalesced lane map: 4 lanes x 64B per row;
//          LDT=40 padded rows), 2-barrier loop. Used by projQK/projV.
//   STG=1: global_load_lds DMA + double-buffered LDS + COUNTED vmcnt (T4):
//          per K-step: issue stage(k+1) -> s_waitcnt vmcnt(8) (waits only
//          for buf[cur], issued one full MFMA phase earlier) -> raw
//          s_barrier -> ds_read+MFMA -> raw s_barrier. No vmcnt(0) in the
//          main loop (round-2 post-mortem: __syncthreads() drains the
//          just-issued prefetch, killing the pipeline; MfmaUtil stuck 25%).
//          LDS linear [128][32] per subtile; bank spread via XOR slot
//          swizzle on the GLOBAL source (stage slot=(l&3)^((l>>3)&3)) and
//          matching ds_read slot (quad^((lrow>>1)&3)) — measured 0 bank
//          conflicts in round 2. fs16 scale applied at fragment-read; fsv
//          plain loads are compiler-tracked, count stays sound (vmcnt(8)
//          drains the 10 oldest = prev stage 8 + 2). Used by scores+gemm3.
// ---------------------------------------------------------------------------

#define LDT 40    // padded LDS row (f16 elems) per 32-k subtile (STG=0)
#define SUB 5120  // 128*LDT elems per subtile (STG=0)

typedef _Float16 f16x8 __attribute__((ext_vector_type(8)));
typedef float f32x4 __attribute__((ext_vector_type(4)));

__device__ __forceinline__ void async16(const _Float16* g, _Float16* l)
{
  __builtin_amdgcn_global_load_lds(
      (const __attribute__((address_space(1))) void*)g,
      (__attribute__((address_space(3))) void*)l, 16, 0, 0);
}

#define WAIT_VM8() asm volatile("s_waitcnt vmcnt(8)" ::: "memory")
#define WAIT_VM0() asm volatile("s_waitcnt vmcnt(0)" ::: "memory")

// ASRC: 0 = plain A; 1 = A scaled by fs16[z][i0>>7][k] (gemm3)
// EPI:  1 = fp16 out + bias by col (bias0 j<512, bias1 else)  [projQK]
//       2 = fp16 out + bias by row (bias0)                     [projV]
//       3 = fp32 out = xadd[o] + alpha*acc                     [gemm3]
//       4 = fused scores: tile col stats -> pmax/psum, S~ fp16  [scores]
template <int ASRC, int EPI, int NSUB, int STG>
__global__ void __launch_bounds__(256, 2) gemm_f16(
    const _Float16* __restrict__ Ap, long lda, long zsa,
    const _Float16* __restrict__ Bp, long ldb, long zsb,
    int kslice,
    const _Float16* __restrict__ fs16, long zsl,
    float* __restrict__ outF, _Float16* __restrict__ outH, long ldc, long zso,
    const float* __restrict__ bias0, const float* __restrict__ bias1,
    const float* __restrict__ xadd,
    float* __restrict__ pmax, float* __restrict__ psum, long zsp,
    float alpha)
{
  constexpr int SMEM_E = (STG == 1) ? (4 * NSUB * 4096) : (2 * NSUB * SUB);
  __shared__ _Float16 smem[SMEM_E];

  const int z = blockIdx.z;
  const long i0 = (long)blockIdx.x * 128;
  const long j0 = (long)blockIdx.y * 128;
  const int t = (int)threadIdx.x;
  const int lane = t & 63;
  const int wv = t >> 6;
  const int quad = lane >> 4;
  const int lrow = lane & 15;
  const int wm = (wv & 1) << 6;
  const int wn = (wv >> 1) << 6;

  f32x4 acc[4][4];
  const f32x4 fz = {0.f, 0.f, 0.f, 0.f};
#pragma unroll
  for (int a = 0; a < 4; a++)
#pragma unroll
    for (int b = 0; b < 4; b++) acc[a][b] = fz;

  if constexpr (STG == 0) {
    // ---------- reg-staged path (coalesced lane map), 2-barrier ----------
    const int r0 = t >> 2;
    const int s0 = (t & 3) << 3;

    const _Float16* gA0 = Ap + z * zsa + (i0 + r0) * lda + s0;
    const _Float16* gA1 = gA0 + 64 * lda;
    const _Float16* gB0 = Bp + z * zsb + (j0 + r0) * ldb + s0;
    const _Float16* gB1 = gB0 + 64 * ldb;
    const int la0 = r0 * LDT + s0;
    const int la1 = (r0 + 64) * LDT + s0;

    for (int kk = 0; kk < kslice; kk += 32 * NSUB) {
      f16x8 va[NSUB][2], vb[NSUB][2];
#pragma unroll
      for (int s = 0; s < NSUB; s++) {
        va[s][0] = *(const f16x8*)(gA0 + kk + 32 * s);
        va[s][1] = *(const f16x8*)(gA1 + kk + 32 * s);
        vb[s][0] = *(const f16x8*)(gB0 + kk + 32 * s);
        vb[s][1] = *(const f16x8*)(gB1 + kk + 32 * s);
      }
      __syncthreads();  // all waves done reading previous tiles
#pragma unroll
      for (int s = 0; s < NSUB; s++) {
        *(f16x8*)&smem[s * SUB + la0] = va[s][0];
        *(f16x8*)&smem[s * SUB + la1] = va[s][1];
        *(f16x8*)&smem[(NSUB + s) * SUB + la0] = vb[s][0];
        *(f16x8*)&smem[(NSUB + s) * SUB + la1] = vb[s][1];
      }
      __syncthreads();

#pragma unroll
      for (int h = 0; h < NSUB; h++) {
        const _Float16* pA = smem + h * SUB;
        const _Float16* pB = smem + (NSUB + h) * SUB;
        f16x8 fa[4], fb[4];
#pragma unroll
        for (int f = 0; f < 4; f++) {
          fa[f] = *(const f16x8*)&pA[(wm + f * 16 + lrow) * LDT + quad * 8];
          fb[f] = *(const f16x8*)&pB[(wn + f * 16 + lrow) * LDT + quad * 8];
        }
#pragma unroll
        for (int fm = 0; fm < 4; fm++)
#pragma unroll
          for (int fn = 0; fn < 4; fn++)
            acc[fm][fn] = __builtin_amdgcn_mfma_f32_16x16x32_f16(fa[fm], fb[fn], acc[fm][fn], 0, 0, 0);
      }
    }
  } else {
    // ---------- STG=1: DMA dbuf + counted vmcnt (no mid-loop drain) -------
    constexpr int KSTEP = 32 * NSUB;
    constexpr int BUFE = 2 * NSUB * 4096;  // f16 elems per buffer (A+B)
    const int crow = lane >> 2;                               // row in 16-row chunk
    const int ks8 = (((lane & 3) ^ ((lane >> 3) & 3)) << 3);  // inverse-swizzled k slot

    // wave wv stages chunks wv (rows 16wv..+15) and wv+4 (rows 64+16wv..+15)
    const _Float16* gAc0 = Ap + z * zsa + (i0 + 16 * wv + crow) * lda + ks8;
    const _Float16* gAc1 = gAc0 + 64 * lda;
    const _Float16* gBc0 = Bp + z * zsb + (j0 + 16 * wv + crow) * ldb + ks8;
    const _Float16* gBc1 = gBc0 + 64 * ldb;
    _Float16* ldsC0 = smem + wv * 512;        // chunk wv dest (wave-uniform)
    _Float16* ldsC1 = smem + (wv + 4) * 512;  // chunk wv+4 dest

    const _Float16* fsZq = nullptr;
    if constexpr (ASRC == 1)
      fsZq = fs16 + z * zsl + (long)blockIdx.x * 4096 + quad * 8;

    // swizzled read slot: k-slice quad*8 sits at slot quad^((lrow>>1)&3)
    const int qs = ((quad ^ ((lrow >> 1) & 3)) << 3);

    auto stage = [&](int buf, int kk) {
#pragma unroll
      for (int s = 0; s < NSUB; s++) {
        const int ab = buf * BUFE + s * 4096;
        const int bb = buf * BUFE + (NSUB + s) * 4096;
        async16(gAc0 + kk + 32 * s, ldsC0 + ab);
        async16(gAc1 + kk + 32 * s, ldsC1 + ab);
        async16(gBc0 + kk + 32 * s, ldsC0 + bb);
        async16(gBc1 + kk + 32 * s, ldsC1 + bb);
      }
    };

    stage(0, 0);  // 8 DMA in flight; no drain — counted in iter 0's vmcnt(8)
    int cur = 0;
    for (int kk = 0; kk < kslice; kk += KSTEP) {
      f16x8 fsv[NSUB];
      if constexpr (ASRC == 1) {
#pragma unroll
        for (int h = 0; h < NSUB; h++)
          fsv[h] = *(const f16x8*)(fsZq + kk + 32 * h);
      }
      if (kk + KSTEP < kslice) {
        stage(cur ^ 1, kk + KSTEP);  // prefetch: stays in flight across barriers
        WAIT_VM8();                  // buf[cur]'s 8 loads (issued last iter) landed
      } else {
        WAIT_VM0();                  // last iter: no prefetch behind, drain all
      }
      __builtin_amdgcn_s_barrier();  // all waves' buf[cur] landed

#pragma unroll
      for (int h = 0; h < NSUB; h++) {
        const _Float16* pA = smem + cur * BUFE + h * 4096;
        const _Float16* pB = smem + cur * BUFE + (NSUB + h) * 4096;
        f16x8 fa[4], fb[4];
#pragma unroll
        for (int f = 0; f < 4; f++) {
          fa[f] = *(const f16x8*)&pA[(wm + f * 16 + lrow) * 32 + qs];
          fb[f] = *(const f16x8*)&pB[(wn + f * 16 + lrow) * 32 + qs];
        }
        if constexpr (ASRC == 1) {
#pragma unroll
          for (int f = 0; f < 4; f++) fa[f] = fa[f] * fsv[h];
        }
#pragma unroll
        for (int fm = 0; fm < 4; fm++)
#pragma unroll
          for (int fn = 0; fn < 4; fn++)
            acc[fm][fn] = __builtin_amdgcn_mfma_f32_16x16x32_f16(fa[fm], fb[fn], acc[fm][fn], 0, 0, 0);
      }
      __builtin_amdgcn_s_barrier();  // all waves done reading buf[cur]
      cur ^= 1;                      // before it is re-staged next iteration
    }
  }

  // D frag: col(j) = lane&15 (+wn+fn*16), row(i) = quad*4 + reg (+wm+fm*16)
  const long obase = (long)z * zso;

  if constexpr (EPI == 1 || EPI == 2) {
#pragma unroll
    for (int fm = 0; fm < 4; fm++) {
      const long gi0 = i0 + wm + fm * 16 + quad * 4;
#pragma unroll
      for (int fn = 0; fn < 4; fn++) {
        const long gj = j0 + wn + fn * 16 + lrow;
        float badd = 0.f;
        if constexpr (EPI == 1) badd = (gj < 512) ? bias0[gj] : bias1[gj - 512];
#pragma unroll
        for (int r = 0; r < 4; r++) {
          float v = acc[fm][fn][r];
          if constexpr (EPI == 1) v += badd;
          else v += bias0[gi0 + r];
          outH[obase + (gi0 + r) * ldc + gj] = (_Float16)v;
        }
      }
    }
  } else if constexpr (EPI == 3) {
#pragma unroll
    for (int fm = 0; fm < 4; fm++) {
      const long gi0 = i0 + wm + fm * 16 + quad * 4;
#pragma unroll
      for (int fn = 0; fn < 4; fn++) {
        const long gj = j0 + wn + fn * 16 + lrow;
#pragma unroll
        for (int r = 0; r < 4; r++) {
          const long o = obase + (gi0 + r) * ldc + gj;
          outF[o] = fmaf(alpha, acc[fm][fn][r], xadd[o]);
        }
      }
    }
  } else {  // EPI == 4: single-exp fused scores epilogue
    __syncthreads();  // done with K-loop LDS
    float* Ls = (float*)smem;
    // LDS float layout: [0,1024) partials (max, then reused for sums)
    //                   [1024,1280) half-maxes, [1280,1408) Mcol
    // stage 1: per-lane per-column-group MAX only (no exp)
#pragma unroll
    for (int fn = 0; fn < 4; fn++) {
      float mx = -3.4e38f;
#pragma unroll
      for (int fm = 0; fm < 4; fm++)
#pragma unroll
        for (int r = 0; r < 4; r++) mx = fmaxf(mx, acc[fm][fn][r]);
      Ls[(wv * 4 + quad) * 64 + fn * 16 + lrow] = mx;
    }
    __syncthreads();
    // stage 2: combine 4 quads -> per (row-half h, col c) max
    {
      const int c = t & 127;
      const int h = t >> 7;
      const int wvv = ((c >> 6) << 1) + h;
      const int wc = c & 63;
      float M = -3.4e38f;
#pragma unroll
      for (int q = 0; q < 4; q++) M = fmaxf(M, Ls[(wvv * 4 + q) * 64 + wc]);
      Ls[1024 + h * 128 + c] = M;
    }
    __syncthreads();
    // stage 3: column max; store pmax; park Mcol in LDS
    if (t < 128) {
      float Mcol = fmaxf(Ls[1024 + t], Ls[1152 + t]);
      pmax[z * zsp + (long)blockIdx.x * 4096 + j0 + t] = Mcol;
      Ls[1280 + t] = Mcol;
    }
    __syncthreads();
    // stage 4: single exp pass — store S~ AND accumulate column partial sums
#pragma unroll
    for (int fn = 0; fn < 4; fn++) {
      const int colc = wn + fn * 16 + lrow;
      const float Mcol = Ls[1280 + colc];
      const long gj = j0 + colc;
      float sm = 0.f;
#pragma unroll
      for (int fm = 0; fm < 4; fm++) {
        const long gi0 = i0 + wm + fm * 16 + quad * 4;
#pragma unroll
        for (int r = 0; r < 4; r++) {
          float e = __expf(acc[fm][fn][r] - Mcol);
          sm += e;
          outH[obase + (gi0 + r) * ldc + gj] = (_Float16)e;
        }
      }
      Ls[(wv * 4 + quad) * 64 + fn * 16 + lrow] = sm;  // reuse partial region
    }
    __syncthreads();
    // stage 5: pure-add reduce of 8 partials per column -> psum
    if (t < 128) {
      const int wc = t & 63;
      const int ch = t >> 6;
      float s = 0.f;
#pragma unroll
      for (int h = 0; h < 2; h++) {
        const int wvv = (ch << 1) + h;
#pragma unroll
        for (int q = 0; q < 4; q++) s += Ls[(wvv * 4 + q) * 64 + wc];
      }
      psum[z * zsp + (long)blockIdx.x * 4096 + j0 + t] = s;
    }
  }
}

__global__ void convert_weights(const float* __restrict__ Wq, const float* __restrict__ Wk,
                                const float* __restrict__ Wv,
                                _Float16* __restrict__ WQK, _Float16* __restrict__ Wv16)
{
  int idx = blockIdx.x * 256 + threadIdx.x;  // 0..786431
  if (idx < 524288)
    WQK[idx] = (_Float16)((idx < 262144) ? Wq[idx] : Wk[idx - 262144]);
  else
    Wv16[idx - 524288] = (_Float16)Wv[idx - 524288];
}

// x [b][c][n] fp32 -> xT [b][n][c] fp16
__global__ void transpose_x(const float* __restrict__ x, _Float16* __restrict__ xT)
{
  __shared__ float tile[32][33];
  const int b = blockIdx.z;
  const int n0 = blockIdx.x * 32;
  const int c0 = blockIdx.y * 32;
  const int tx = threadIdx.x;
  const int ty = threadIdx.y;
  const float* xb = x + (long)b * 2097152;
#pragma unroll
  for (int k = 0; k < 4; k++)
    tile[ty + k * 8][tx] = xb[(long)(c0 + ty + k * 8) * 4096 + n0 + tx];
  __syncthreads();
  _Float16* xTb = xT + (long)b * 2097152;
#pragma unroll
  for (int k = 0; k < 4; k++)
    xTb[(long)(n0 + ty + k * 8) * 512 + c0 + tx] = (_Float16)tile[tx][ty + k * 8];
}

// fused: lse[z][m] from 32 tile partials, then fs16[z][tile][m] = exp(pmax-lse)
__global__ void stats_scale(const float* __restrict__ pmax, const float* __restrict__ psum,
                            _Float16* __restrict__ fs16)
{
  const int idx = blockIdx.x * 256 + threadIdx.x;  // grid 64: z*4096+m
  const int z = idx >> 12;
  const int m = idx & 4095;
  const float* pm = pmax + (long)z * 131072 + m;
  const float* ps = psum + (long)z * 131072 + m;
  float M = -3.4e38f, S = 0.f;
  for (int i = 0; i < 32; i++) {
    float m2 = pm[(long)i * 4096], s2 = ps[(long)i * 4096];
    float nm = fmaxf(M, m2);
    S = S * __expf(M - nm) + s2 * __expf(m2 - nm);
    M = nm;
  }
  const float lse = M + __logf(S);
  _Float16* fo = fs16 + (long)z * 131072 + m;
  for (int i = 0; i < 32; i++)
    fo[(long)i * 4096] = (_Float16)__expf(pm[(long)i * 4096] - lse);
}

extern "C" void kernel_launch(void* const* d_in, const int* in_sizes, int n_in,
                              void* d_out, int out_size, void* d_ws, size_t ws_size,
                              hipStream_t stream)
{
  const float* x  = (const float*)d_in[0];
  const float* Wq = (const float*)d_in[1];
  const float* bq = (const float*)d_in[2];
  const float* Wk = (const float*)d_in[3];
  const float* bk = (const float*)d_in[4];
  const float* Wv = (const float*)d_in[5];
  const float* bv = (const float*)d_in[6];
  float* out = (float*)d_out;

  char* w = (char*)d_ws;
  _Float16* WQK   = (_Float16*)(w + 0);          //  1,048,576
  _Float16* Wv16  = (_Float16*)(w + 1048576);    //    524,288
  _Float16* xT    = (_Float16*)(w + 1572864);    // 16,777,216
  _Float16* QK    = (_Float16*)(w + 18350080);   // 33,554,432
  _Float16* Vt    = (_Float16*)(w + 51904512);   // 16,777,216
  float*    pmaxB = (float*)   (w + 68747264);   //  2,097,152
  float*    psumB = (float*)   (w + 70844416);   //  2,097,152
  _Float16* fs16  = (_Float16*)(w + 72941568);   //  1,048,576 = [z][32][4096] fp16
  _Float16* S16   = (_Float16*)(w + 75038720);   // 134,217,728
  // total 209,256,448 B

  convert_weights<<<3072, 256, 0, stream>>>(Wq, Wk, Wv, WQK, Wv16);
  transpose_x<<<dim3(128, 16, 4), dim3(32, 8), 0, stream>>>(x, xT);

  // projQK: QK[z][n][j] fp16, j<512 Q(+bq), j>=512 K(+bk)
  gemm_f16<0, 1, 2, 0><<<dim3(32, 8, 4), 256, 0, stream>>>(
      xT, 512, 2097152L, WQK, 512, 0L, 512, nullptr, 0L,
      nullptr, QK, 1024, 4194304L, bq, bk, nullptr, nullptr, nullptr, 0L, 0.f);
  // projV: Vt[z][c][m] fp16 (+bv by row)
  gemm_f16<0, 2, 2, 0><<<dim3(4, 32, 4), 256, 0, stream>>>(
      Wv16, 512, 0L, xT, 512, 2097152L, 512, nullptr, 0L,
      nullptr, Vt, 4096, 2097152L, bv, nullptr, nullptr, nullptr, nullptr, 0L, 0.f);
  // scores (STG=1 counted): S~[z][n][m] fp16 + tile col stats
  gemm_f16<0, 4, 2, 1><<<dim3(32, 32, 4), 256, 0, stream>>>(
      QK, 1024, 4194304L, QK + 512, 1024, 4194304L, 512, nullptr, 0L,
      nullptr, S16, 4096, 16777216L, nullptr, nullptr, nullptr,
      pmaxB, psumB, 131072L, 0.f);
  stats_scale<<<64, 256, 0, stream>>>(pmaxB, psumB, fs16);
  // gemm3 (STG=1 counted vmcnt dbuf, K-step 64, 64 KB LDS, 2 blocks/CU):
  // out = x.flat + 0.1*(S~*fs16)·Vt^T
  gemm_f16<1, 3, 2, 1><<<dim3(32, 4, 4), 256, 0, stream>>>(
      S16, 4096, 16777216L, Vt, 4096, 2097152L, 4096, fs16, 131072L,
      out, nullptr, 512, 2097152L, nullptr, nullptr, x, nullptr, nullptr, 0L, 0.1f);
}